// Round 13
// baseline (256.493 us; speedup 1.0000x reference)
//
#include <hip/hip_runtime.h>
#include <stdint.h>

#define B_ 2
#define S_ 2048
#define E_ 1024
#define H_ 16
#define HD_ 64
#define FF_ 4096
#define M_ 4096   // B*S
#define LOG2E_ 1.44269504f

typedef short bf16x8 __attribute__((ext_vector_type(8)));
typedef float f32x4  __attribute__((ext_vector_type(4)));
typedef short shortx4 __attribute__((ext_vector_type(4)));

#define MFMA16(a,b,c) __builtin_amdgcn_mfma_f32_16x16x32_bf16(a,b,c,0,0,0)

__device__ __forceinline__ short f2bf(float f) {
  uint32_t u = __builtin_bit_cast(uint32_t, f);
  u += 0x7fffu + ((u >> 16) & 1u);
  return (short)(u >> 16);
}
__device__ __forceinline__ float bf2f(short b) {
  uint32_t u = ((uint32_t)(uint16_t)b) << 16;
  return __builtin_bit_cast(float, u);
}
__device__ __forceinline__ float exp2_hw(float x) {
  float r;
  asm("v_exp_f32 %0, %1" : "=v"(r) : "v"(x));
  return r;
}

// DPP row-rotate (16-lane row), VALU-pipe cross-lane: ROW_ROR:N = 0x120|N
template<int CTRL>
__device__ __forceinline__ float dpp_ror(float x) {
  return __builtin_bit_cast(float,
    __builtin_amdgcn_update_dpp(0, __builtin_bit_cast(int, x), CTRL, 0xF, 0xF, true));
}
__device__ __forceinline__ float dpp_max16(float v) {
  v = fmaxf(v, dpp_ror<0x128>(v));
  v = fmaxf(v, dpp_ror<0x124>(v));
  v = fmaxf(v, dpp_ror<0x122>(v));
  v = fmaxf(v, dpp_ror<0x121>(v));
  return v;
}
__device__ __forceinline__ float dpp_sum16(float v) {
  v += dpp_ror<0x128>(v);
  v += dpp_ror<0x124>(v);
  v += dpp_ror<0x122>(v);
  v += dpp_ror<0x121>(v);
  return v;
}

// async global->LDS, 16B per lane, wave-uniform LDS base + lane*16 (per-lane global src)
#define GLDS16(g, l) __builtin_amdgcn_global_load_lds( \
    (const __attribute__((address_space(1))) unsigned int*)(g), \
    (__attribute__((address_space(3))) unsigned int*)(l), 16, 0, 0)

// ---------------------------------------------------------------- fused cast f32->bf16 (all 5 arrays)
__global__ void cast_all(const float* __restrict__ x, const float* __restrict__ wkqv,
                         const float* __restrict__ wo, const float* __restrict__ wup,
                         const float* __restrict__ wdown,
                         short* __restrict__ xb, short* __restrict__ wkqvb,
                         short* __restrict__ wob, short* __restrict__ wupb,
                         short* __restrict__ wdownb) {
  const int stride = gridDim.x * blockDim.x;
  for (int i = blockIdx.x * blockDim.x + threadIdx.x; i < 4194304; i += stride) {
    const int e = i << 2;
    const float* src; short* dst; int off;
    if (e < 4194304)       { src = x;     dst = xb;     off = e; }
    else if (e < 7340032)  { src = wkqv;  dst = wkqvb;  off = e - 4194304; }
    else if (e < 8388608)  { src = wo;    dst = wob;    off = e - 7340032; }
    else if (e < 12582912) { src = wup;   dst = wupb;   off = e - 8388608; }
    else                   { src = wdown; dst = wdownb; off = e - 12582912; }
    float4 v = *(const float4*)(src + off);
    shortx4 o;
    o.x = f2bf(v.x); o.y = f2bf(v.y); o.z = f2bf(v.z); o.w = f2bf(v.w);
    *(shortx4*)(dst + off) = o;
  }
}

// ---------------------------------------------------------------- GEMM 256x256, BK=64, 8 waves
// Phase-structured (T3+T4+T2+T5): 4 phases/K-tile, counted vmcnt(2) once per tile,
// XOR-swizzled LDS (phys_slot = logical ^ (row&7), pre-swizzled global source),
// 2 global_load_lds staged per phase, 16 MFMA per phase in setprio brackets.
// A: M x K bf16 rm.  Bw: N x K bf16 rm.  C: M x N bf16.  EPI: 0 none, 1 bias+relu.
template<int EPI>
__global__ __launch_bounds__(512, 2) void gemm256_bt(
    const short* __restrict__ A, const short* __restrict__ Bw,
    short* __restrict__ C, const float* __restrict__ bias,
    int M, int N, int K)
{
  __shared__ short Al[2][16384];   // [buf][256 rows x 64 cols]
  __shared__ short Bl[2][16384];
  const int tid = threadIdx.x;
  const int w = tid >> 6, lane = tid & 63;
  const int lr = lane & 15, lg = lane >> 4;
  const int ntiles = N >> 8;
  const int nwg = gridDim.x;
  const int bid = blockIdx.x;
  const int swz = (bid & 7) * (nwg >> 3) + (bid >> 3);
  const int tn = swz % ntiles, tm = swz / ntiles;
  const int m0 = tm << 8, n0 = tn << 8;
  const int wrm = (w >> 2) << 7;       // 0 / 128
  const int wcn = (w & 3) << 6;        // 0 / 64 / 128 / 192

  // staging: issue i stages chunk c = w + i*8 (8 rows x 128B, 64 lanes x 16B).
  // lane: row-in-chunk = lane>>3 (= R&7), phys 16B-slot = lane&7,
  // global col pre-swizzled: logical slot = (lane&7) ^ (R&7).
  const int srow = lane >> 3;
  const int scol = ((lane & 7) ^ srow) << 3;   // shorts
  const short* Ag[4]; const short* Bg[4];
  #pragma unroll
  for (int i = 0; i < 4; ++i) {
    const int c = w + i * 8;
    Ag[i] = A  + (size_t)(m0 + c * 8 + srow) * K + scol;
    Bg[i] = Bw + (size_t)(n0 + c * 8 + srow) * K + scol;
  }

  f32x4 acc[8][4] = {};
  const int T = K >> 6;

  // prologue: tile 0 -> buf 0 (8 loads)
  #pragma unroll
  for (int i = 0; i < 4; ++i) {
    GLDS16(Ag[i], &Al[0][(w + i * 8) * 512]);
    GLDS16(Bg[i], &Bl[0][(w + i * 8) * 512]);
  }

  for (int t = 0; t < T; ++t) {
    const int buf = t & 1;
    const bool more = (t + 1 < T);
    const int k1 = (t + 1) << 6;

    bf16x8 af[8], bf01[4], bf23[4];
    // swizzled ds_read helpers (logical slot = ks*4+lg, phys = ^ (row&7))
    const int ph0 = lg ^ (lr & 7);        // ks=0
    const int ph1 = (4 + lg) ^ (lr & 7);  // ks=1

    // ---- phase a: stage 2; vmcnt(2) -> tile t fully in LDS; barrier; reads; MFMA q(0-3 x 0-1)
    if (more) {
      GLDS16(Ag[0] + k1, &Al[buf ^ 1][(w + 0) * 512]);
      GLDS16(Ag[1] + k1, &Al[buf ^ 1][(w + 8) * 512]);
      asm volatile("s_waitcnt vmcnt(2)" ::: "memory");
    } else {
      asm volatile("s_waitcnt vmcnt(0)" ::: "memory");
    }
    __builtin_amdgcn_sched_barrier(0);
    __builtin_amdgcn_s_barrier();

    #pragma unroll
    for (int i = 0; i < 4; ++i) {
      const int R = wrm + i * 16 + lr;
      af[i * 2]     = *(const bf16x8*)&Al[buf][R * 64 + ph0 * 8];
      af[i * 2 + 1] = *(const bf16x8*)&Al[buf][R * 64 + ph1 * 8];
    }
    #pragma unroll
    for (int j = 0; j < 2; ++j) {
      const int R = wcn + j * 16 + lr;
      bf01[j * 2]     = *(const bf16x8*)&Bl[buf][R * 64 + ph0 * 8];
      bf01[j * 2 + 1] = *(const bf16x8*)&Bl[buf][R * 64 + ph1 * 8];
    }
    __builtin_amdgcn_s_setprio(1);
    #pragma unroll
    for (int i = 0; i < 4; ++i)
      #pragma unroll
      for (int j = 0; j < 2; ++j) {
        acc[i][j] = MFMA16(af[i * 2],     bf01[j * 2],     acc[i][j]);
        acc[i][j] = MFMA16(af[i * 2 + 1], bf01[j * 2 + 1], acc[i][j]);
      }
    __builtin_amdgcn_s_setprio(0);
    __builtin_amdgcn_s_barrier();

    // ---- phase b: stage 2; reads B j2-3; MFMA q(0-3 x 2-3)
    if (more) {
      GLDS16(Ag[2] + k1, &Al[buf ^ 1][(w + 16) * 512]);
      GLDS16(Ag[3] + k1, &Al[buf ^ 1][(w + 24) * 512]);
    }
    #pragma unroll
    for (int j = 0; j < 2; ++j) {
      const int R = wcn + (j + 2) * 16 + lr;
      bf23[j * 2]     = *(const bf16x8*)&Bl[buf][R * 64 + ph0 * 8];
      bf23[j * 2 + 1] = *(const bf16x8*)&Bl[buf][R * 64 + ph1 * 8];
    }
    __builtin_amdgcn_s_setprio(1);
    #pragma unroll
    for (int i = 0; i < 4; ++i)
      #pragma unroll
      for (int j = 0; j < 2; ++j) {
        acc[i][j + 2] = MFMA16(af[i * 2],     bf23[j * 2],     acc[i][j + 2]);
        acc[i][j + 2] = MFMA16(af[i * 2 + 1], bf23[j * 2 + 1], acc[i][j + 2]);
      }
    __builtin_amdgcn_s_setprio(0);
    __builtin_amdgcn_s_barrier();

    // ---- phase c: stage 2; reads A i4-7; MFMA q(4-7 x 2-3)
    if (more) {
      GLDS16(Bg[0] + k1, &Bl[buf ^ 1][(w + 0) * 512]);
      GLDS16(Bg[1] + k1, &Bl[buf ^ 1][(w + 8) * 512]);
    }
    #pragma unroll
    for (int i = 0; i < 4; ++i) {
      const int R = wrm + (i + 4) * 16 + lr;
      af[i * 2]     = *(const bf16x8*)&Al[buf][R * 64 + ph0 * 8];
      af[i * 2 + 1] = *(const bf16x8*)&Al[buf][R * 64 + ph1 * 8];
    }
    __builtin_amdgcn_s_setprio(1);
    #pragma unroll
    for (int i = 0; i < 4; ++i)
      #pragma unroll
      for (int j = 0; j < 2; ++j) {
        acc[i + 4][j + 2] = MFMA16(af[i * 2],     bf23[j * 2],     acc[i + 4][j + 2]);
        acc[i + 4][j + 2] = MFMA16(af[i * 2 + 1], bf23[j * 2 + 1], acc[i + 4][j + 2]);
      }
    __builtin_amdgcn_s_setprio(0);
    __builtin_amdgcn_s_barrier();

    // ---- phase d: stage 2; reads B j0-1; MFMA q(4-7 x 0-1)
    if (more) {
      GLDS16(Bg[2] + k1, &Bl[buf ^ 1][(w + 16) * 512]);
      GLDS16(Bg[3] + k1, &Bl[buf ^ 1][(w + 24) * 512]);
    }
    #pragma unroll
    for (int j = 0; j < 2; ++j) {
      const int R = wcn + j * 16 + lr;
      bf01[j * 2]     = *(const bf16x8*)&Bl[buf][R * 64 + ph0 * 8];
      bf01[j * 2 + 1] = *(const bf16x8*)&Bl[buf][R * 64 + ph1 * 8];
    }
    __builtin_amdgcn_s_setprio(1);
    #pragma unroll
    for (int i = 0; i < 4; ++i)
      #pragma unroll
      for (int j = 0; j < 2; ++j) {
        acc[i + 4][j] = MFMA16(af[i * 2],     bf01[j * 2],     acc[i + 4][j]);
        acc[i + 4][j] = MFMA16(af[i * 2 + 1], bf01[j * 2 + 1], acc[i + 4][j]);
      }
    __builtin_amdgcn_s_setprio(0);
    __builtin_amdgcn_s_barrier();
  }

  // ---- epilogue
  #pragma unroll
  for (int j = 0; j < 4; ++j) {
    const int col = n0 + wcn + j * 16 + lr;
    float bv = 0.f;
    if constexpr (EPI == 1) bv = bias[col];
    #pragma unroll
    for (int i = 0; i < 8; ++i) {
      #pragma unroll
      for (int r = 0; r < 4; ++r) {
        const int row = m0 + wrm + i * 16 + lg * 4 + r;
        float v = acc[i][j][r] + bv;
        if constexpr (EPI == 1) v = fmaxf(v, 0.f);
        C[(size_t)row * N + col] = f2bf(v);
      }
    }
  }
}

// ---------------------------------------------------------------- GEMM  C = A * Bw^T
// 128x128 tile, BK=32, double-buffered with counted vmcnt (round-8 verified).
template<int SK, int EPI, typename OutT>
__global__ __launch_bounds__(256) void gemm_bt(
    const short* __restrict__ A, const short* __restrict__ Bw,
    OutT* __restrict__ C0, OutT* __restrict__ C1, const float* __restrict__ bias,
    int M, int N, int K)
{
  __shared__ short Al[2][128 * 32];
  __shared__ short Bl[2][128 * 32];
  const int tid  = threadIdx.x;
  const int w    = tid >> 6, lane = tid & 63;
  const int ntiles = N >> 7;
  const int nwg = gridDim.x;
  const int bid = blockIdx.x;
  const int swz = (bid & 7) * (nwg >> 3) + (bid >> 3);
  const int tn = swz % ntiles, tm = swz / ntiles;
  const int m0 = tm << 7, n0 = tn << 7;
  const int wr = (w >> 1) << 6, wc = (w & 1) << 6;
  const int lr = lane & 15, lk = (lane >> 4) << 3;
  const int ra = lane >> 2, colA = (lane & 3) << 3;

  const int kper = K / SK;
  const int kbeg = (SK > 1) ? (int)blockIdx.y * kper : 0;
  const int T = kper >> 5;
  OutT* __restrict__ C = (SK > 1 && blockIdx.y) ? C1 : C0;

  const short* Ag0 = A  + (size_t)(m0 + w * 16 + ra) * K + colA;
  const short* Ag1 = A  + (size_t)(m0 + (w + 4) * 16 + ra) * K + colA;
  const short* Bg0 = Bw + (size_t)(n0 + w * 16 + ra) * K + colA;
  const short* Bg1 = Bw + (size_t)(n0 + (w + 4) * 16 + ra) * K + colA;

  f32x4 acc[4][4] = {};

  {
    const int k0 = kbeg;
    GLDS16(Ag0 + k0, &Al[0][w * 512]);
    GLDS16(Ag1 + k0, &Al[0][(w + 4) * 512]);
    GLDS16(Bg0 + k0, &Bl[0][w * 512]);
    GLDS16(Bg1 + k0, &Bl[0][(w + 4) * 512]);
  }

  for (int it = 0; it < T; ++it) {
    const int buf = it & 1;
    if (it + 1 < T) {
      const int k1 = kbeg + ((it + 1) << 5);
      GLDS16(Ag0 + k1, &Al[buf ^ 1][w * 512]);
      GLDS16(Ag1 + k1, &Al[buf ^ 1][(w + 4) * 512]);
      GLDS16(Bg0 + k1, &Bl[buf ^ 1][w * 512]);
      GLDS16(Bg1 + k1, &Bl[buf ^ 1][(w + 4) * 512]);
      asm volatile("s_waitcnt vmcnt(4)" ::: "memory");
    } else {
      asm volatile("s_waitcnt vmcnt(0)" ::: "memory");
    }
    __builtin_amdgcn_sched_barrier(0);
    __builtin_amdgcn_s_barrier();      // all waves' tile-it loads are in LDS

    bf16x8 af[4], bfr[4];
    #pragma unroll
    for (int i = 0; i < 4; ++i)
      af[i] = *(const bf16x8*)&Al[buf][(wr + i * 16 + lr) * 32 + lk];
    #pragma unroll
    for (int j = 0; j < 4; ++j)
      bfr[j] = *(const bf16x8*)&Bl[buf][(wc + j * 16 + lr) * 32 + lk];
    #pragma unroll
    for (int i = 0; i < 4; ++i)
      #pragma unroll
      for (int j = 0; j < 4; ++j)
        acc[i][j] = MFMA16(af[i], bfr[j], acc[i][j]);

    __builtin_amdgcn_s_barrier();      // readers done before iter it+1 overwrites buf
  }

  const int lg = lane >> 4;
  #pragma unroll
  for (int j = 0; j < 4; ++j) {
    const int col = n0 + wc + j * 16 + lr;
    float bv = 0.f;
    if constexpr (SK == 1 && EPI != 0) bv = bias[col];
    #pragma unroll
    for (int i = 0; i < 4; ++i) {
      #pragma unroll
      for (int r = 0; r < 4; ++r) {
        const int row = m0 + wr + i * 16 + lg * 4 + r;
        float v = acc[i][j][r] + bv;
        if constexpr (SK == 1 && EPI == 1) v = fmaxf(v, 0.f);
        if constexpr (sizeof(OutT) == 2) C[(size_t)row * N + col] = f2bf(v);
        else                             C[(size_t)row * N + col] = v;
      }
    }
  }
}

// ---------------------------------------------------------------- causal flash attention
// Round-12 verified: paired (p,31-p), 8 waves, K/V LDS double-buffer, 1 barrier/iter.
__global__ __launch_bounds__(512) void attn_kernel(
    const short* __restrict__ kqv, short* __restrict__ out)
{
  __shared__ short Kt[2][64][72];     // K rows (k) x d, double-buffered
  __shared__ short Vt[2][64][72];     // transposed: d x k, col k XOR-swizzled, dbuf
  __shared__ short Pl[8][16][72];     // per-wave P tile

  const int tid = threadIdx.x, w = tid >> 6, lane = tid & 63;
  const int wt = w & 3;               // wave index within its tile team
  const int p = blockIdx.x;           // 0..15, heaviest (p=0) dispatched first
  const int bh = blockIdx.y;          // 0..31
  const int b = bh >> 4, h = bh & 15;
  const int q0 = ((w < 4) ? (31 - p) : p) << 6;
  const int nkb = 32 - p;             // k-blocks for the hi tile (superset of lo's)
  const int lr = lane & 15, lg = lane >> 4;

  // Q fragment: rows q0 + wt*16 + lr, d = ks*32 + lg*8 ..+8; pre-scaled by 1/8 (exact)
  const size_t rowq = (size_t)(b * S_ + q0 + wt * 16 + lr) * 3072 + 1024 + h * 64;
  bf16x8 qf[2];
  qf[0] = *(const bf16x8*)&kqv[rowq + lg * 8];
  qf[1] = *(const bf16x8*)&kqv[rowq + 32 + lg * 8];
  #pragma unroll
  for (int ks = 0; ks < 2; ++ks)
    #pragma unroll
    for (int e = 0; e < 8; ++e)
      qf[ks][e] = f2bf(bf2f(qf[ks][e]) * 0.125f);

  f32x4 acc[4] = {};
  float m_run[4], l_run[4];
  #pragma unroll
  for (int r = 0; r < 4; ++r) { m_run[r] = -1e30f; l_run[r] = 0.f; }

  const int skk = tid >> 3;           // 0..63 staging row (k), one per 8 threads
  const int sc  = (tid & 7) << 3;     // staging col (d)
  const int vws = (tid & 7) << 3;     // V write swizzle: 8*((sc+e)>>3 & 7)
  const int vkc = skk ^ vws;          // V write column (swizzled)
  const short* gstage = kqv + (size_t)b * S_ * 3072 + h * 64 + sc;

  // prologue: tile 0 -> buf 0
  {
    bf16x8 kreg = *(const bf16x8*)&gstage[(size_t)skk * 3072];
    bf16x8 vreg = *(const bf16x8*)&gstage[(size_t)skk * 3072 + 2048];
    *(bf16x8*)&Kt[0][skk][sc] = kreg;
    #pragma unroll
    for (int e = 0; e < 8; ++e) Vt[0][sc + e][vkc] = vreg[e];
  }
  __syncthreads();

  for (int kbi = 0; kbi < nkb; ++kbi) {
    const int buf = kbi & 1;
    const int kb = kbi << 6;

    // ---- issue next tile's global loads (latency hides under process)
    bf16x8 kreg, vreg;
    const bool more = (kbi + 1 < nkb);
    if (more) {
      const size_t gb = (size_t)(((kbi + 1) << 6) + skk) * 3072;
      kreg = *(const bf16x8*)&gstage[gb];
      vreg = *(const bf16x8*)&gstage[gb + 2048];
    }

    // ---- per-wave processing on buf
    if (kb <= q0 + wt * 16 + 15) {
      f32x4 sacc[4] = {};
      __builtin_amdgcn_s_setprio(1);
      #pragma unroll
      for (int jt = 0; jt < 4; ++jt) {
        #pragma unroll
        for (int ks = 0; ks < 2; ++ks) {
          bf16x8 kf = *(const bf16x8*)&Kt[buf][jt * 16 + lr][ks * 32 + lg * 8];
          sacc[jt] = MFMA16(qf[ks], kf, sacc[jt]);
        }
      }
      __builtin_amdgcn_s_setprio(0);
      const bool full = (kb + 63 <= q0 + wt * 16);
      float rmax[4];
      if (full) {
        #pragma unroll
        for (int r = 0; r < 4; ++r)
          rmax[r] = fmaxf(fmaxf(sacc[0][r], sacc[1][r]), fmaxf(sacc[2][r], sacc[3][r]));
      } else {
        #pragma unroll
        for (int r = 0; r < 4; ++r) rmax[r] = -1e30f;
        #pragma unroll
        for (int jt = 0; jt < 4; ++jt) {
          const int kpos = kb + jt * 16 + lr;
          #pragma unroll
          for (int r = 0; r < 4; ++r) {
            const int qrow = q0 + wt * 16 + lg * 4 + r;
            float v = (kpos <= qrow) ? sacc[jt][r] : -1e30f;
            sacc[jt][r] = v;
            rmax[r] = fmaxf(rmax[r], v);
          }
        }
      }
      #pragma unroll
      for (int r = 0; r < 4; ++r) rmax[r] = dpp_max16(rmax[r]);
      int need = 0;
      #pragma unroll
      for (int r = 0; r < 4; ++r) need |= (rmax[r] > m_run[r] + 8.f) ? 1 : 0;
      if (__any(need)) {
        #pragma unroll
        for (int r = 0; r < 4; ++r) {
          const float mn = fmaxf(m_run[r], rmax[r]);
          const float al = exp2_hw((m_run[r] - mn) * LOG2E_);
          m_run[r] = mn;
          l_run[r] *= al;
          #pragma unroll
          for (int dt = 0; dt < 4; ++dt) acc[dt][r] *= al;
        }
      }
      float m2[4], rsum[4];
      #pragma unroll
      for (int r = 0; r < 4; ++r) { m2[r] = m_run[r] * LOG2E_; rsum[r] = 0.f; }
      #pragma unroll
      for (int jt = 0; jt < 4; ++jt)
        #pragma unroll
        for (int r = 0; r < 4; ++r) {
          const float pv = exp2_hw(__builtin_fmaf(sacc[jt][r], LOG2E_, -m2[r]));
          sacc[jt][r] = pv;
          rsum[r] += pv;
        }
      #pragma unroll
      for (int r = 0; r < 4; ++r) { rsum[r] = dpp_sum16(rsum[r]); l_run[r] += rsum[r]; }
      #pragma unroll
      for (int jt = 0; jt < 4; ++jt) {
        uint32_t w01, w23;
        asm("v_cvt_pk_bf16_f32 %0, %1, %2" : "=v"(w01) : "v"(sacc[jt][0]), "v"(sacc[jt][1]));
        asm("v_cvt_pk_bf16_f32 %0, %1, %2" : "=v"(w23) : "v"(sacc[jt][2]), "v"(sacc[jt][3]));
        Pl[w][lg * 4 + 0][jt * 16 + lr] = (short)(w01 & 0xffffu);
        Pl[w][lg * 4 + 1][jt * 16 + lr] = (short)(w01 >> 16);
        Pl[w][lg * 4 + 2][jt * 16 + lr] = (short)(w23 & 0xffffu);
        Pl[w][lg * 4 + 3][jt * 16 + lr] = (short)(w23 >> 16);
      }
      bf16x8 pa[2];
      pa[0] = *(const bf16x8*)&Pl[w][lr][lg * 8];
      pa[1] = *(const bf16x8*)&Pl[w][lr][32 + lg * 8];
      __builtin_amdgcn_s_setprio(1);
      #pragma unroll
      for (int dt = 0; dt < 4; ++dt) {
        const int vswz = (2 * dt + (lr >> 3)) << 3;
        #pragma unroll
        for (int ks = 0; ks < 2; ++ks) {
          bf16x8 vb = *(const bf16x8*)&Vt[buf][dt * 16 + lr][(ks * 32 + lg * 8) ^ vswz];
          acc[dt] = MFMA16(pa[ks], vb, acc[dt]);
        }
      }
      __builtin_amdgcn_s_setprio(0);
    }

    // ---- write prefetched tile into the other buffer
    if (more) {
      *(bf16x8*)&Kt[buf ^ 1][skk][sc] = kreg;
      #pragma unroll
      for (int e = 0; e < 8; ++e) Vt[buf ^ 1][sc + e][vkc] = vreg[e];
    }
    __syncthreads();   // orders: buf^1 writes before next read; buf reads before next write
  }

  // ---- epilogue: normalize and store (each wave owns unique rows)
  #pragma unroll
  for (int dt = 0; dt < 4; ++dt) {
    #pragma unroll
    for (int r = 0; r < 4; ++r) {
      const int d = h * 64 + dt * 16 + lr;
      const int q_row = q0 + wt * 16 + lg * 4 + r;
      out[(size_t)(b * S_ + q_row) * E_ + d] = f2bf(acc[dt][r] / l_run[r]);
    }
  }
}

// ---------------------------------------------------------------- residual + LayerNorm (split-K fold)
template<int FINAL>
__global__ __launch_bounds__(256) void ln_kernel(
    const float* __restrict__ y0, const float* __restrict__ y1,
    const float* __restrict__ bias, const void* __restrict__ res,
    const float* __restrict__ gam, const float* __restrict__ bet,
    void* __restrict__ outp)
{
  const int row = blockIdx.x, tid = threadIdx.x, lane = tid & 63, w = tid >> 6;
  float4 a = ((const float4*)(y0 + (size_t)row * E_))[tid];
  float4 c = ((const float4*)(y1 + (size_t)row * E_))[tid];
  float r[4] = {a.x + c.x, a.y + c.y, a.z + c.z, a.w + c.w};
  if constexpr (FINAL) {
    float4 bi = ((const float4*)bias)[tid];
    shortx4 rb = ((const shortx4*)((const short*)res + (size_t)row * E_))[tid];
    r[0] += bi.x + bf2f(rb.x); r[1] += bi.y + bf2f(rb.y);
    r[2] += bi.z + bf2f(rb.z); r[3] += bi.w + bf2f(rb.w);
  } else {
    float4 rv = ((const float4*)((const float*)res + (size_t)row * E_))[tid];
    r[0] += rv.x; r[1] += rv.y; r[2] += rv.z; r[3] += rv.w;
  }
  float s  = r[0] + r[1] + r[2] + r[3];
  float ss = r[0]*r[0] + r[1]*r[1] + r[2]*r[2] + r[3]*r[3];
  #pragma unroll
  for (int m = 32; m >= 1; m >>= 1) { s += __shfl_xor(s, m); ss += __shfl_xor(ss, m); }
  __shared__ float red[8];
  if (lane == 0) { red[w] = s; red[4 + w] = ss; }
  __syncthreads();
  s  = red[0] + red[1] + red[2] + red[3];
  ss = red[4] + red[5] + red[6] + red[7];
  const float mu  = s * (1.f / E_);
  const float var = ss * (1.f / E_) - mu * mu;
  const float rs  = rsqrtf(var + 1e-6f);
  float4 gv = ((const float4*)gam)[tid];
  float4 bv = ((const float4*)bet)[tid];
  float o0 = (r[0] - mu) * rs * gv.x + bv.x;
  float o1 = (r[1] - mu) * rs * gv.y + bv.y;
  float o2 = (r[2] - mu) * rs * gv.z + bv.z;
  float o3 = (r[3] - mu) * rs * gv.w + bv.w;
  if constexpr (FINAL) {
    float4 o; o.x = o0; o.y = o1; o.z = o2; o.w = o3;
    ((float4*)((float*)outp + (size_t)row * E_))[tid] = o;
  } else {
    shortx4 o; o.x = f2bf(o0); o.y = f2bf(o1); o.z = f2bf(o2); o.w = f2bf(o3);
    ((shortx4*)((short*)outp + (size_t)row * E_))[tid] = o;
  }
}

// ---------------------------------------------------------------- launch
// ws timeline (MB): [0-8 xb][8-14 wkqvb][14-16 wob][16-24 wupb][24-32 wdownb]
//   [32-56 kqv] -> attn [64-72 attno] -> proj [32-48 p0][48-64 p1] -> ln0 [72-80 xln]
//   -> up [32-64 hbuf] -> down [0-16 d0][80-96 d1] -> ln1.  Peak 96 MB.
extern "C" void kernel_launch(void* const* d_in, const int* in_sizes, int n_in,
                              void* d_out, int out_size, void* d_ws, size_t ws_size,
                              hipStream_t stream) {
  const float* x      = (const float*)d_in[0];
  const float* w_kqv  = (const float*)d_in[2];
  const float* w_o    = (const float*)d_in[3];
  const float* w_up   = (const float*)d_in[4];
  const float* b_up   = (const float*)d_in[5];
  const float* w_down = (const float*)d_in[6];
  const float* b_down = (const float*)d_in[7];
  const float* g1     = (const float*)d_in[8];
  const float* b1     = (const float*)d_in[9];
  const float* g2     = (const float*)d_in[10];
  const float* b2     = (const float*)d_in[11];
  float* out = (float*)d_out;

  char* ws = (char*)d_ws;
  short* xb     = (short*)(ws);
  short* wkqvb  = (short*)(ws + ((size_t)8  << 20));
  short* wob    = (short*)(ws + ((size_t)14 << 20));
  short* wupb   = (short*)(ws + ((size_t)16 << 20));
  short* wdownb = (short*)(ws + ((size_t)24 << 20));
  short* kqv    = (short*)(ws + ((size_t)32 << 20));
  float* proj0  = (float*)(ws + ((size_t)32 << 20));
  float* proj1  = (float*)(ws + ((size_t)48 << 20));
  short* hbuf   = (short*)(ws + ((size_t)32 << 20));
  short* attno  = (short*)(ws + ((size_t)64 << 20));
  short* xln    = (short*)(ws + ((size_t)72 << 20));
  float* down0  = (float*)(ws);
  float* down1  = (float*)(ws + ((size_t)80 << 20));

  cast_all<<<2048, 256, 0, stream>>>(x, w_kqv, w_o, w_up, w_down,
                                     xb, wkqvb, wob, wupb, wdownb);

  gemm256_bt<0><<<192, 512, 0, stream>>>(xb, wkqvb, kqv, nullptr, M_, 3 * E_, E_);
  attn_kernel<<<dim3(16, B_ * H_), 512, 0, stream>>>(kqv, attno);
  gemm_bt<2, 0, float><<<dim3(256, 2), 256, 0, stream>>>(attno, wob, proj0, proj1, nullptr, M_, E_, E_);
  ln_kernel<0><<<M_, 256, 0, stream>>>(proj0, proj1, nullptr, x, g1, b1, xln);
  gemm256_bt<1><<<256, 512, 0, stream>>>(xln, wupb, hbuf, b_up, M_, FF_, E_);
  gemm_bt<2, 0, float><<<dim3(256, 2), 256, 0, stream>>>(hbuf, wdownb, down0, down1, nullptr, M_, E_, FF_);
  ln_kernel<1><<<M_, 256, 0, stream>>>(down0, down1, b_down, xln, g2, b2, out);
}

// Round 14
// 234.673 us; speedup vs baseline: 1.0930x; 1.0930x over previous
//
#include <hip/hip_runtime.h>
#include <stdint.h>

#define B_ 2
#define S_ 2048
#define E_ 1024
#define H_ 16
#define HD_ 64
#define FF_ 4096
#define M_ 4096   // B*S
#define LOG2E_ 1.44269504f

typedef short bf16x8 __attribute__((ext_vector_type(8)));
typedef float f32x4  __attribute__((ext_vector_type(4)));
typedef short shortx4 __attribute__((ext_vector_type(4)));

#define MFMA16(a,b,c) __builtin_amdgcn_mfma_f32_16x16x32_bf16(a,b,c,0,0,0)

__device__ __forceinline__ short f2bf(float f) {
  uint32_t u = __builtin_bit_cast(uint32_t, f);
  u += 0x7fffu + ((u >> 16) & 1u);
  return (short)(u >> 16);
}
__device__ __forceinline__ float bf2f(short b) {
  uint32_t u = ((uint32_t)(uint16_t)b) << 16;
  return __builtin_bit_cast(float, u);
}
__device__ __forceinline__ float exp2_hw(float x) {
  float r;
  asm("v_exp_f32 %0, %1" : "=v"(r) : "v"(x));
  return r;
}

// DPP row-rotate (16-lane row), VALU-pipe cross-lane: ROW_ROR:N = 0x120|N
template<int CTRL>
__device__ __forceinline__ float dpp_ror(float x) {
  return __builtin_bit_cast(float,
    __builtin_amdgcn_update_dpp(0, __builtin_bit_cast(int, x), CTRL, 0xF, 0xF, true));
}
__device__ __forceinline__ float dpp_max16(float v) {
  v = fmaxf(v, dpp_ror<0x128>(v));
  v = fmaxf(v, dpp_ror<0x124>(v));
  v = fmaxf(v, dpp_ror<0x122>(v));
  v = fmaxf(v, dpp_ror<0x121>(v));
  return v;
}
__device__ __forceinline__ float dpp_sum16(float v) {
  v += dpp_ror<0x128>(v);
  v += dpp_ror<0x124>(v);
  v += dpp_ror<0x122>(v);
  v += dpp_ror<0x121>(v);
  return v;
}

// async global->LDS, 16B per lane, wave-uniform LDS base + lane*16 (per-lane global src)
#define GLDS16(g, l) __builtin_amdgcn_global_load_lds( \
    (const __attribute__((address_space(1))) unsigned int*)(g), \
    (__attribute__((address_space(3))) unsigned int*)(l), 16, 0, 0)

// ---------------------------------------------------------------- fused cast f32->bf16 (all 5 arrays)
__global__ void cast_all(const float* __restrict__ x, const float* __restrict__ wkqv,
                         const float* __restrict__ wo, const float* __restrict__ wup,
                         const float* __restrict__ wdown,
                         short* __restrict__ xb, short* __restrict__ wkqvb,
                         short* __restrict__ wob, short* __restrict__ wupb,
                         short* __restrict__ wdownb) {
  const int stride = gridDim.x * blockDim.x;
  for (int i = blockIdx.x * blockDim.x + threadIdx.x; i < 4194304; i += stride) {
    const int e = i << 2;
    const float* src; short* dst; int off;
    if (e < 4194304)       { src = x;     dst = xb;     off = e; }
    else if (e < 7340032)  { src = wkqv;  dst = wkqvb;  off = e - 4194304; }
    else if (e < 8388608)  { src = wo;    dst = wob;    off = e - 7340032; }
    else if (e < 12582912) { src = wup;   dst = wupb;   off = e - 8388608; }
    else                   { src = wdown; dst = wdownb; off = e - 12582912; }
    float4 v = *(const float4*)(src + off);
    shortx4 o;
    o.x = f2bf(v.x); o.y = f2bf(v.y); o.z = f2bf(v.z); o.w = f2bf(v.w);
    *(shortx4*)(dst + off) = o;
  }
}

// ---------------------------------------------------------------- GEMM 256x256, BK=64, 8 waves
// Phase-structured (T3+T4+T2+T5). FULL-TILE prefetch distance: ALL 8 of tile
// t+1's global_load_lds are issued at phase a, then vmcnt(8) waits only for
// tile t's 8 loads (issued one full tile earlier, ~4 phases of cover).
// XOR-swizzled LDS (phys 16B-slot = logical ^ (row&7), pre-swizzled source).
template<int EPI>
__global__ __launch_bounds__(512, 2) void gemm256_bt(
    const short* __restrict__ A, const short* __restrict__ Bw,
    short* __restrict__ C, const float* __restrict__ bias,
    int M, int N, int K)
{
  __shared__ short Al[2][16384];   // [buf][256 rows x 64 cols]
  __shared__ short Bl[2][16384];
  const int tid = threadIdx.x;
  const int w = tid >> 6, lane = tid & 63;
  const int lr = lane & 15, lg = lane >> 4;
  const int ntiles = N >> 8;
  const int nwg = gridDim.x;
  const int bid = blockIdx.x;
  const int swz = (bid & 7) * (nwg >> 3) + (bid >> 3);
  const int tn = swz % ntiles, tm = swz / ntiles;
  const int m0 = tm << 8, n0 = tn << 8;
  const int wrm = (w >> 2) << 7;       // 0 / 128
  const int wcn = (w & 3) << 6;        // 0 / 64 / 128 / 192

  // staging: issue i stages chunk c = w + i*8 (8 rows x 128B, 64 lanes x 16B).
  const int srow = lane >> 3;
  const int scol = ((lane & 7) ^ srow) << 3;   // pre-swizzled source col (shorts)
  const short* Ag[4]; const short* Bg[4];
  #pragma unroll
  for (int i = 0; i < 4; ++i) {
    const int c = w + i * 8;
    Ag[i] = A  + (size_t)(m0 + c * 8 + srow) * K + scol;
    Bg[i] = Bw + (size_t)(n0 + c * 8 + srow) * K + scol;
  }

  f32x4 acc[8][4] = {};
  const int T = K >> 6;

  // prologue: tile 0 -> buf 0 (8 loads)
  #pragma unroll
  for (int i = 0; i < 4; ++i) {
    GLDS16(Ag[i], &Al[0][(w + i * 8) * 512]);
    GLDS16(Bg[i], &Bl[0][(w + i * 8) * 512]);
  }

  for (int t = 0; t < T; ++t) {
    const int buf = t & 1;
    const bool more = (t + 1 < T);
    const int k1 = (t + 1) << 6;

    bf16x8 af[8], bf01[4], bf23[4];
    const int ph0 = lg ^ (lr & 7);        // ks=0 swizzled slot
    const int ph1 = (4 + lg) ^ (lr & 7);  // ks=1

    // ---- phase a: issue ALL 8 of t+1; vmcnt(8) drains tile t's 8 (full-tile
    // distance); barrier; reads A i0-3 + B j0-1; MFMA q(0-3 x 0-1)
    if (more) {
      #pragma unroll
      for (int i = 0; i < 4; ++i) {
        GLDS16(Ag[i] + k1, &Al[buf ^ 1][(w + i * 8) * 512]);
        GLDS16(Bg[i] + k1, &Bl[buf ^ 1][(w + i * 8) * 512]);
      }
      asm volatile("s_waitcnt vmcnt(8)" ::: "memory");
    } else {
      asm volatile("s_waitcnt vmcnt(0)" ::: "memory");
    }
    __builtin_amdgcn_sched_barrier(0);
    __builtin_amdgcn_s_barrier();

    #pragma unroll
    for (int i = 0; i < 4; ++i) {
      const int R = wrm + i * 16 + lr;
      af[i * 2]     = *(const bf16x8*)&Al[buf][R * 64 + ph0 * 8];
      af[i * 2 + 1] = *(const bf16x8*)&Al[buf][R * 64 + ph1 * 8];
    }
    #pragma unroll
    for (int j = 0; j < 2; ++j) {
      const int R = wcn + j * 16 + lr;
      bf01[j * 2]     = *(const bf16x8*)&Bl[buf][R * 64 + ph0 * 8];
      bf01[j * 2 + 1] = *(const bf16x8*)&Bl[buf][R * 64 + ph1 * 8];
    }
    __builtin_amdgcn_s_setprio(1);
    #pragma unroll
    for (int i = 0; i < 4; ++i)
      #pragma unroll
      for (int j = 0; j < 2; ++j) {
        acc[i][j] = MFMA16(af[i * 2],     bf01[j * 2],     acc[i][j]);
        acc[i][j] = MFMA16(af[i * 2 + 1], bf01[j * 2 + 1], acc[i][j]);
      }
    __builtin_amdgcn_s_setprio(0);
    __builtin_amdgcn_s_barrier();

    // ---- phase b: reads B j2-3; MFMA q(0-3 x 2-3)
    #pragma unroll
    for (int j = 0; j < 2; ++j) {
      const int R = wcn + (j + 2) * 16 + lr;
      bf23[j * 2]     = *(const bf16x8*)&Bl[buf][R * 64 + ph0 * 8];
      bf23[j * 2 + 1] = *(const bf16x8*)&Bl[buf][R * 64 + ph1 * 8];
    }
    __builtin_amdgcn_s_setprio(1);
    #pragma unroll
    for (int i = 0; i < 4; ++i)
      #pragma unroll
      for (int j = 0; j < 2; ++j) {
        acc[i][j + 2] = MFMA16(af[i * 2],     bf23[j * 2],     acc[i][j + 2]);
        acc[i][j + 2] = MFMA16(af[i * 2 + 1], bf23[j * 2 + 1], acc[i][j + 2]);
      }
    __builtin_amdgcn_s_setprio(0);
    __builtin_amdgcn_s_barrier();

    // ---- phase c: reads A i4-7; MFMA q(4-7 x 2-3)
    #pragma unroll
    for (int i = 0; i < 4; ++i) {
      const int R = wrm + (i + 4) * 16 + lr;
      af[i * 2]     = *(const bf16x8*)&Al[buf][R * 64 + ph0 * 8];
      af[i * 2 + 1] = *(const bf16x8*)&Al[buf][R * 64 + ph1 * 8];
    }
    __builtin_amdgcn_s_setprio(1);
    #pragma unroll
    for (int i = 0; i < 4; ++i)
      #pragma unroll
      for (int j = 0; j < 2; ++j) {
        acc[i + 4][j + 2] = MFMA16(af[i * 2],     bf23[j * 2],     acc[i + 4][j + 2]);
        acc[i + 4][j + 2] = MFMA16(af[i * 2 + 1], bf23[j * 2 + 1], acc[i + 4][j + 2]);
      }
    __builtin_amdgcn_s_setprio(0);
    __builtin_amdgcn_s_barrier();

    // ---- phase d: MFMA q(4-7 x 0-1) (bf01 still live)
    __builtin_amdgcn_s_setprio(1);
    #pragma unroll
    for (int i = 0; i < 4; ++i)
      #pragma unroll
      for (int j = 0; j < 2; ++j) {
        acc[i + 4][j] = MFMA16(af[i * 2],     bf01[j * 2],     acc[i + 4][j]);
        acc[i + 4][j] = MFMA16(af[i * 2 + 1], bf01[j * 2 + 1], acc[i + 4][j]);
      }
    __builtin_amdgcn_s_setprio(0);
    __builtin_amdgcn_s_barrier();
  }

  // ---- epilogue
  #pragma unroll
  for (int j = 0; j < 4; ++j) {
    const int col = n0 + wcn + j * 16 + lr;
    float bv = 0.f;
    if constexpr (EPI == 1) bv = bias[col];
    #pragma unroll
    for (int i = 0; i < 8; ++i) {
      #pragma unroll
      for (int r = 0; r < 4; ++r) {
        const int row = m0 + wrm + i * 16 + lg * 4 + r;
        float v = acc[i][j][r] + bv;
        if constexpr (EPI == 1) v = fmaxf(v, 0.f);
        C[(size_t)row * N + col] = f2bf(v);
      }
    }
  }
}

// ---------------------------------------------------------------- GEMM  C = A * Bw^T
// 128x128 tile, BK=32, double-buffered with counted vmcnt (round-8 verified).
template<int SK, int EPI, typename OutT>
__global__ __launch_bounds__(256) void gemm_bt(
    const short* __restrict__ A, const short* __restrict__ Bw,
    OutT* __restrict__ C0, OutT* __restrict__ C1, const float* __restrict__ bias,
    int M, int N, int K)
{
  __shared__ short Al[2][128 * 32];
  __shared__ short Bl[2][128 * 32];
  const int tid  = threadIdx.x;
  const int w    = tid >> 6, lane = tid & 63;
  const int ntiles = N >> 7;
  const int nwg = gridDim.x;
  const int bid = blockIdx.x;
  const int swz = (bid & 7) * (nwg >> 3) + (bid >> 3);
  const int tn = swz % ntiles, tm = swz / ntiles;
  const int m0 = tm << 7, n0 = tn << 7;
  const int wr = (w >> 1) << 6, wc = (w & 1) << 6;
  const int lr = lane & 15, lk = (lane >> 4) << 3;
  const int ra = lane >> 2, colA = (lane & 3) << 3;

  const int kper = K / SK;
  const int kbeg = (SK > 1) ? (int)blockIdx.y * kper : 0;
  const int T = kper >> 5;
  OutT* __restrict__ C = (SK > 1 && blockIdx.y) ? C1 : C0;

  const short* Ag0 = A  + (size_t)(m0 + w * 16 + ra) * K + colA;
  const short* Ag1 = A  + (size_t)(m0 + (w + 4) * 16 + ra) * K + colA;
  const short* Bg0 = Bw + (size_t)(n0 + w * 16 + ra) * K + colA;
  const short* Bg1 = Bw + (size_t)(n0 + (w + 4) * 16 + ra) * K + colA;

  f32x4 acc[4][4] = {};

  {
    const int k0 = kbeg;
    GLDS16(Ag0 + k0, &Al[0][w * 512]);
    GLDS16(Ag1 + k0, &Al[0][(w + 4) * 512]);
    GLDS16(Bg0 + k0, &Bl[0][w * 512]);
    GLDS16(Bg1 + k0, &Bl[0][(w + 4) * 512]);
  }

  for (int it = 0; it < T; ++it) {
    const int buf = it & 1;
    if (it + 1 < T) {
      const int k1 = kbeg + ((it + 1) << 5);
      GLDS16(Ag0 + k1, &Al[buf ^ 1][w * 512]);
      GLDS16(Ag1 + k1, &Al[buf ^ 1][(w + 4) * 512]);
      GLDS16(Bg0 + k1, &Bl[buf ^ 1][w * 512]);
      GLDS16(Bg1 + k1, &Bl[buf ^ 1][(w + 4) * 512]);
      asm volatile("s_waitcnt vmcnt(4)" ::: "memory");
    } else {
      asm volatile("s_waitcnt vmcnt(0)" ::: "memory");
    }
    __builtin_amdgcn_sched_barrier(0);
    __builtin_amdgcn_s_barrier();      // all waves' tile-it loads are in LDS

    bf16x8 af[4], bfr[4];
    #pragma unroll
    for (int i = 0; i < 4; ++i)
      af[i] = *(const bf16x8*)&Al[buf][(wr + i * 16 + lr) * 32 + lk];
    #pragma unroll
    for (int j = 0; j < 4; ++j)
      bfr[j] = *(const bf16x8*)&Bl[buf][(wc + j * 16 + lr) * 32 + lk];
    #pragma unroll
    for (int i = 0; i < 4; ++i)
      #pragma unroll
      for (int j = 0; j < 4; ++j)
        acc[i][j] = MFMA16(af[i], bfr[j], acc[i][j]);

    __builtin_amdgcn_s_barrier();      // readers done before iter it+1 overwrites buf
  }

  const int lg = lane >> 4;
  #pragma unroll
  for (int j = 0; j < 4; ++j) {
    const int col = n0 + wc + j * 16 + lr;
    float bv = 0.f;
    if constexpr (SK == 1 && EPI != 0) bv = bias[col];
    #pragma unroll
    for (int i = 0; i < 4; ++i) {
      #pragma unroll
      for (int r = 0; r < 4; ++r) {
        const int row = m0 + wr + i * 16 + lg * 4 + r;
        float v = acc[i][j][r] + bv;
        if constexpr (SK == 1 && EPI == 1) v = fmaxf(v, 0.f);
        if constexpr (sizeof(OutT) == 2) C[(size_t)row * N + col] = f2bf(v);
        else                             C[(size_t)row * N + col] = v;
      }
    }
  }
}

// ---------------------------------------------------------------- causal flash attention
// Round-12 verified: paired (p,31-p), 8 waves, K/V LDS double-buffer, 1 barrier/iter.
__global__ __launch_bounds__(512) void attn_kernel(
    const short* __restrict__ kqv, short* __restrict__ out)
{
  __shared__ short Kt[2][64][72];     // K rows (k) x d, double-buffered
  __shared__ short Vt[2][64][72];     // transposed: d x k, col k XOR-swizzled, dbuf
  __shared__ short Pl[8][16][72];     // per-wave P tile

  const int tid = threadIdx.x, w = tid >> 6, lane = tid & 63;
  const int wt = w & 3;               // wave index within its tile team
  const int p = blockIdx.x;           // 0..15, heaviest (p=0) dispatched first
  const int bh = blockIdx.y;          // 0..31
  const int b = bh >> 4, h = bh & 15;
  const int q0 = ((w < 4) ? (31 - p) : p) << 6;
  const int nkb = 32 - p;             // k-blocks for the hi tile (superset of lo's)
  const int lr = lane & 15, lg = lane >> 4;

  // Q fragment: rows q0 + wt*16 + lr, d = ks*32 + lg*8 ..+8; pre-scaled by 1/8 (exact)
  const size_t rowq = (size_t)(b * S_ + q0 + wt * 16 + lr) * 3072 + 1024 + h * 64;
  bf16x8 qf[2];
  qf[0] = *(const bf16x8*)&kqv[rowq + lg * 8];
  qf[1] = *(const bf16x8*)&kqv[rowq + 32 + lg * 8];
  #pragma unroll
  for (int ks = 0; ks < 2; ++ks)
    #pragma unroll
    for (int e = 0; e < 8; ++e)
      qf[ks][e] = f2bf(bf2f(qf[ks][e]) * 0.125f);

  f32x4 acc[4] = {};
  float m_run[4], l_run[4];
  #pragma unroll
  for (int r = 0; r < 4; ++r) { m_run[r] = -1e30f; l_run[r] = 0.f; }

  const int skk = tid >> 3;           // 0..63 staging row (k), one per 8 threads
  const int sc  = (tid & 7) << 3;     // staging col (d)
  const int vws = (tid & 7) << 3;     // V write swizzle: 8*((sc+e)>>3 & 7)
  const int vkc = skk ^ vws;          // V write column (swizzled)
  const short* gstage = kqv + (size_t)b * S_ * 3072 + h * 64 + sc;

  // prologue: tile 0 -> buf 0
  {
    bf16x8 kreg = *(const bf16x8*)&gstage[(size_t)skk * 3072];
    bf16x8 vreg = *(const bf16x8*)&gstage[(size_t)skk * 3072 + 2048];
    *(bf16x8*)&Kt[0][skk][sc] = kreg;
    #pragma unroll
    for (int e = 0; e < 8; ++e) Vt[0][sc + e][vkc] = vreg[e];
  }
  __syncthreads();

  for (int kbi = 0; kbi < nkb; ++kbi) {
    const int buf = kbi & 1;
    const int kb = kbi << 6;

    // ---- issue next tile's global loads (latency hides under process)
    bf16x8 kreg, vreg;
    const bool more = (kbi + 1 < nkb);
    if (more) {
      const size_t gb = (size_t)(((kbi + 1) << 6) + skk) * 3072;
      kreg = *(const bf16x8*)&gstage[gb];
      vreg = *(const bf16x8*)&gstage[gb + 2048];
    }

    // ---- per-wave processing on buf
    if (kb <= q0 + wt * 16 + 15) {
      f32x4 sacc[4] = {};
      __builtin_amdgcn_s_setprio(1);
      #pragma unroll
      for (int jt = 0; jt < 4; ++jt) {
        #pragma unroll
        for (int ks = 0; ks < 2; ++ks) {
          bf16x8 kf = *(const bf16x8*)&Kt[buf][jt * 16 + lr][ks * 32 + lg * 8];
          sacc[jt] = MFMA16(qf[ks], kf, sacc[jt]);
        }
      }
      __builtin_amdgcn_s_setprio(0);
      const bool full = (kb + 63 <= q0 + wt * 16);
      float rmax[4];
      if (full) {
        #pragma unroll
        for (int r = 0; r < 4; ++r)
          rmax[r] = fmaxf(fmaxf(sacc[0][r], sacc[1][r]), fmaxf(sacc[2][r], sacc[3][r]));
      } else {
        #pragma unroll
        for (int r = 0; r < 4; ++r) rmax[r] = -1e30f;
        #pragma unroll
        for (int jt = 0; jt < 4; ++jt) {
          const int kpos = kb + jt * 16 + lr;
          #pragma unroll
          for (int r = 0; r < 4; ++r) {
            const int qrow = q0 + wt * 16 + lg * 4 + r;
            float v = (kpos <= qrow) ? sacc[jt][r] : -1e30f;
            sacc[jt][r] = v;
            rmax[r] = fmaxf(rmax[r], v);
          }
        }
      }
      #pragma unroll
      for (int r = 0; r < 4; ++r) rmax[r] = dpp_max16(rmax[r]);
      int need = 0;
      #pragma unroll
      for (int r = 0; r < 4; ++r) need |= (rmax[r] > m_run[r] + 8.f) ? 1 : 0;
      if (__any(need)) {
        #pragma unroll
        for (int r = 0; r < 4; ++r) {
          const float mn = fmaxf(m_run[r], rmax[r]);
          const float al = exp2_hw((m_run[r] - mn) * LOG2E_);
          m_run[r] = mn;
          l_run[r] *= al;
          #pragma unroll
          for (int dt = 0; dt < 4; ++dt) acc[dt][r] *= al;
        }
      }
      float m2[4], rsum[4];
      #pragma unroll
      for (int r = 0; r < 4; ++r) { m2[r] = m_run[r] * LOG2E_; rsum[r] = 0.f; }
      #pragma unroll
      for (int jt = 0; jt < 4; ++jt)
        #pragma unroll
        for (int r = 0; r < 4; ++r) {
          const float pv = exp2_hw(__builtin_fmaf(sacc[jt][r], LOG2E_, -m2[r]));
          sacc[jt][r] = pv;
          rsum[r] += pv;
        }
      #pragma unroll
      for (int r = 0; r < 4; ++r) { rsum[r] = dpp_sum16(rsum[r]); l_run[r] += rsum[r]; }
      #pragma unroll
      for (int jt = 0; jt < 4; ++jt) {
        uint32_t w01, w23;
        asm("v_cvt_pk_bf16_f32 %0, %1, %2" : "=v"(w01) : "v"(sacc[jt][0]), "v"(sacc[jt][1]));
        asm("v_cvt_pk_bf16_f32 %0, %1, %2" : "=v"(w23) : "v"(sacc[jt][2]), "v"(sacc[jt][3]));
        Pl[w][lg * 4 + 0][jt * 16 + lr] = (short)(w01 & 0xffffu);
        Pl[w][lg * 4 + 1][jt * 16 + lr] = (short)(w01 >> 16);
        Pl[w][lg * 4 + 2][jt * 16 + lr] = (short)(w23 & 0xffffu);
        Pl[w][lg * 4 + 3][jt * 16 + lr] = (short)(w23 >> 16);
      }
      bf16x8 pa[2];
      pa[0] = *(const bf16x8*)&Pl[w][lr][lg * 8];
      pa[1] = *(const bf16x8*)&Pl[w][lr][32 + lg * 8];
      __builtin_amdgcn_s_setprio(1);
      #pragma unroll
      for (int dt = 0; dt < 4; ++dt) {
        const int vswz = (2 * dt + (lr >> 3)) << 3;
        #pragma unroll
        for (int ks = 0; ks < 2; ++ks) {
          bf16x8 vb = *(const bf16x8*)&Vt[buf][dt * 16 + lr][(ks * 32 + lg * 8) ^ vswz];
          acc[dt] = MFMA16(pa[ks], vb, acc[dt]);
        }
      }
      __builtin_amdgcn_s_setprio(0);
    }

    // ---- write prefetched tile into the other buffer
    if (more) {
      *(bf16x8*)&Kt[buf ^ 1][skk][sc] = kreg;
      #pragma unroll
      for (int e = 0; e < 8; ++e) Vt[buf ^ 1][sc + e][vkc] = vreg[e];
    }
    __syncthreads();   // orders: buf^1 writes before next read; buf reads before next write
  }

  // ---- epilogue: normalize and store (each wave owns unique rows)
  #pragma unroll
  for (int dt = 0; dt < 4; ++dt) {
    #pragma unroll
    for (int r = 0; r < 4; ++r) {
      const int d = h * 64 + dt * 16 + lr;
      const int q_row = q0 + wt * 16 + lg * 4 + r;
      out[(size_t)(b * S_ + q_row) * E_ + d] = f2bf(acc[dt][r] / l_run[r]);
    }
  }
}

// ---------------------------------------------------------------- residual + LayerNorm (split-K fold)
template<int FINAL>
__global__ __launch_bounds__(256) void ln_kernel(
    const float* __restrict__ y0, const float* __restrict__ y1,
    const float* __restrict__ bias, const void* __restrict__ res,
    const float* __restrict__ gam, const float* __restrict__ bet,
    void* __restrict__ outp)
{
  const int row = blockIdx.x, tid = threadIdx.x, lane = tid & 63, w = tid >> 6;
  float4 a = ((const float4*)(y0 + (size_t)row * E_))[tid];
  float4 c = ((const float4*)(y1 + (size_t)row * E_))[tid];
  float r[4] = {a.x + c.x, a.y + c.y, a.z + c.z, a.w + c.w};
  if constexpr (FINAL) {
    float4 bi = ((const float4*)bias)[tid];
    shortx4 rb = ((const shortx4*)((const short*)res + (size_t)row * E_))[tid];
    r[0] += bi.x + bf2f(rb.x); r[1] += bi.y + bf2f(rb.y);
    r[2] += bi.z + bf2f(rb.z); r[3] += bi.w + bf2f(rb.w);
  } else {
    float4 rv = ((const float4*)((const float*)res + (size_t)row * E_))[tid];
    r[0] += rv.x; r[1] += rv.y; r[2] += rv.z; r[3] += rv.w;
  }
  float s  = r[0] + r[1] + r[2] + r[3];
  float ss = r[0]*r[0] + r[1]*r[1] + r[2]*r[2] + r[3]*r[3];
  #pragma unroll
  for (int m = 32; m >= 1; m >>= 1) { s += __shfl_xor(s, m); ss += __shfl_xor(ss, m); }
  __shared__ float red[8];
  if (lane == 0) { red[w] = s; red[4 + w] = ss; }
  __syncthreads();
  s  = red[0] + red[1] + red[2] + red[3];
  ss = red[4] + red[5] + red[6] + red[7];
  const float mu  = s * (1.f / E_);
  const float var = ss * (1.f / E_) - mu * mu;
  const float rs  = rsqrtf(var + 1e-6f);
  float4 gv = ((const float4*)gam)[tid];
  float4 bv = ((const float4*)bet)[tid];
  float o0 = (r[0] - mu) * rs * gv.x + bv.x;
  float o1 = (r[1] - mu) * rs * gv.y + bv.y;
  float o2 = (r[2] - mu) * rs * gv.z + bv.z;
  float o3 = (r[3] - mu) * rs * gv.w + bv.w;
  if constexpr (FINAL) {
    float4 o; o.x = o0; o.y = o1; o.z = o2; o.w = o3;
    ((float4*)((float*)outp + (size_t)row * E_))[tid] = o;
  } else {
    shortx4 o; o.x = f2bf(o0); o.y = f2bf(o1); o.z = f2bf(o2); o.w = f2bf(o3);
    ((shortx4*)((short*)outp + (size_t)row * E_))[tid] = o;
  }
}

// ---------------------------------------------------------------- launch
// ws timeline (MB): [0-8 xb][8-14 wkqvb][14-16 wob][16-24 wupb][24-32 wdownb]
//   [32-56 kqv] -> attn [64-72 attno] -> proj [32-48 p0][48-64 p1] -> ln0 [72-80 xln]
//   -> up [32-64 hbuf] -> down [0-16 d0][80-96 d1] -> ln1.  Peak 96 MB.
extern "C" void kernel_launch(void* const* d_in, const int* in_sizes, int n_in,
                              void* d_out, int out_size, void* d_ws, size_t ws_size,
                              hipStream_t stream) {
  const float* x      = (const float*)d_in[0];
  const float* w_kqv  = (const float*)d_in[2];
  const float* w_o    = (const float*)d_in[3];
  const float* w_up   = (const float*)d_in[4];
  const float* b_up   = (const float*)d_in[5];
  const float* w_down = (const float*)d_in[6];
  const float* b_down = (const float*)d_in[7];
  const float* g1     = (const float*)d_in[8];
  const float* b1     = (const float*)d_in[9];
  const float* g2     = (const float*)d_in[10];
  const float* b2     = (const float*)d_in[11];
  float* out = (float*)d_out;

  char* ws = (char*)d_ws;
  short* xb     = (short*)(ws);
  short* wkqvb  = (short*)(ws + ((size_t)8  << 20));
  short* wob    = (short*)(ws + ((size_t)14 << 20));
  short* wupb   = (short*)(ws + ((size_t)16 << 20));
  short* wdownb = (short*)(ws + ((size_t)24 << 20));
  short* kqv    = (short*)(ws + ((size_t)32 << 20));
  float* proj0  = (float*)(ws + ((size_t)32 << 20));
  float* proj1  = (float*)(ws + ((size_t)48 << 20));
  short* hbuf   = (short*)(ws + ((size_t)32 << 20));
  short* attno  = (short*)(ws + ((size_t)64 << 20));
  short* xln    = (short*)(ws + ((size_t)72 << 20));
  float* down0  = (float*)(ws);
  float* down1  = (float*)(ws + ((size_t)80 << 20));

  cast_all<<<2048, 256, 0, stream>>>(x, w_kqv, w_o, w_up, w_down,
                                     xb, wkqvb, wob, wupb, wdownb);

  gemm_bt<1, 0, short><<<24 * 32, 256, 0, stream>>>(xb, wkqvb, kqv, nullptr, nullptr, M_, 3 * E_, E_);
  attn_kernel<<<dim3(16, B_ * H_), 512, 0, stream>>>(kqv, attno);
  gemm_bt<2, 0, float><<<dim3(256, 2), 256, 0, stream>>>(attno, wob, proj0, proj1, nullptr, M_, E_, E_);
  ln_kernel<0><<<M_, 256, 0, stream>>>(proj0, proj1, nullptr, x, g1, b1, xln);
  gemm256_bt<1><<<256, 512, 0, stream>>>(xln, wupb, hbuf, b_up, M_, FF_, E_);
  gemm_bt<2, 0, float><<<dim3(256, 2), 256, 0, stream>>>(hbuf, wdownb, down0, down1, nullptr, M_, E_, FF_);
  ln_kernel<1><<<M_, 256, 0, stream>>>(down0, down1, b_down, xln, g2, b2, out);
}